// Round 1
// baseline (1471.788 us; speedup 1.0000x reference)
//
#include <hip/hip_runtime.h>

// ScaleLasryLions: per-scale separable parabolic closing/opening, alpha blend.
// x:(8,192,192,4,32) f32, coef:(1,32), c:(1,1,32), alpha:(1,1,1,32) -> out same shape as x.
//
// Design (R1): one fully-fused kernel per scale. Block = one (b,ch) image tile.
// All 4 morph passes are "vertical" (window along the row index of the current
// LDS buffer); each pass writes its output TRANSPOSED so the next axis becomes
// the row axis. Pipeline per branch: dilH -> dilW -> eroH -> eroW (closing),
// eroH -> eroW -> dilH -> dilW (opening), blended at the end.
// Thread computes NH consecutive outputs along the pass axis from a register
// window of NH+L-1 values -> LDS reads/output ~ (NH+L-1)/NH, VALU 2L-1 -> VALU bound.

constexpr int HH = 192, WW = 192, CHN = 32, SCST = 128; // S*C stride per (b,h,w)

constexpr int cdiv_(int a, int b) { return (a + b - 1) / b; }
constexpr int r4_(int a) { return (a + 3) & ~3; }
// smallest NH so one sweep of the pass fits in NT work items
constexpr int pickNH(int R, int C, int NT) {
    for (int nh = 1; nh <= R; ++nh)
        if (cdiv_(R, nh) * C <= NT) return nh;
    return R;
}
constexpr float s2_of(int si) { // scale^2 for scales {0.25, 0.75, 1.75, 3.75} (all exact fp32)
    return si == 0 ? 0.0625f : si == 1 ? 0.5625f : si == 2 ? 3.0625f : 14.0625f;
}

// Compute NH outputs along the row axis at fixed column c.
// out[r] = opt_{j<L} in[r+j][c] +/- tap[j], tap[j] = (-(j-SW)^2/S2) * kmul (const-folded).
template <int L, int SW, bool DIL, int NH, int R, int PIT>
__device__ __forceinline__ void pass_compute(const float* __restrict__ in, int r0, int c,
                                             float kmul, float (&acc)[NH]) {
    constexpr float S2 = 0; // placeholder (specialized below via template arg trick not needed)
    (void)S2;
    float wb[NH + L - 1];
#pragma unroll
    for (int t = 0; t < NH + L - 1; ++t) {
        int rr = r0 + t;
        if (rr > R + L - 2) rr = R + L - 2; // clamp for partial last segment (outputs masked)
        wb[t] = in[rr * PIT + c];
    }
#pragma unroll
    for (int j = 0; j < L; ++j) {
        float v = (float)(j - SW);
        // S2 folded in by caller through kmul2 path: we pass kmul already; S2 via template param below
        float fb = -(v * v); // completed with /S2 at call site via kmul scaling? NO - see wrapper.
        (void)fb;
        break;
    }
    (void)kmul;
}

// NOTE: the generic version above is unused; the real implementation carries S2 as a
// template-selected constant through SI. Kept minimal below.

template <int L, int SW, int SI, bool DIL, int NH, int R, int PIT>
__device__ __forceinline__ void pass_compute_si(const float* __restrict__ in, int r0, int c,
                                                float kmul, float (&acc)[NH]) {
    constexpr float S2 = s2_of(SI);
    float wb[NH + L - 1];
#pragma unroll
    for (int t = 0; t < NH + L - 1; ++t) {
        int rr = r0 + t;
        if (rr > R + L - 2) rr = R + L - 2;
        wb[t] = in[rr * PIT + c];
    }
#pragma unroll
    for (int j = 0; j < L; ++j) {
        float v = (float)(j - SW);
        float tp = (-(v * v) / S2) * kmul; // (-(j-w)^2/s^2) folds to a literal; 1 v_mul per j
#pragma unroll
        for (int o = 0; o < NH; ++o) {
            float t = DIL ? wb[o + j] + tp : wb[o + j] - tp;
            if (j == 0) acc[o] = t;
            else acc[o] = DIL ? fmaxf(acc[o], t) : fminf(acc[o], t);
        }
    }
}

template <int L, int SW, int SI, bool DIL, int NH, int R, int C, int PIT, int POUT, int NT>
__device__ __forceinline__ void pass_lds(const float* __restrict__ in, float* __restrict__ outT,
                                         float kmul, int tid) {
    constexpr int nseg = cdiv_(R, NH);
    for (int item = tid; item < nseg * C; item += NT) { // single iteration by construction
        int c = item % C, r0 = (item / C) * NH;
        float acc[NH];
        pass_compute_si<L, SW, SI, DIL, NH, R, PIT>(in, r0, c, kmul, acc);
#pragma unroll
        for (int o = 0; o < NH; ++o)
            if (r0 + o < R) outT[c * POUT + (r0 + o)] = acc[o]; // transposed write
    }
}

template <int SI, int SW, int TH, int TW, int NT, int MW>
__launch_bounds__(NT, MW) __global__
void lasry_kernel(const float* __restrict__ x, const float* __restrict__ coef,
                  const float* __restrict__ cin, const float* __restrict__ ain,
                  float* __restrict__ out) {
    constexpr int L = 2 * SW + 1;
    constexpr int IH = TH + 4 * SW, IW = TW + 4 * SW;
    constexpr int R1 = TH + 2 * SW, C1 = IW;      // dil/ero along H; out transposed [w][h]
    constexpr int R2 = TW + 2 * SW, C2 = R1;      // along W; out transposed [h][w]
    constexpr int R3 = TH,          C3 = R2;      // along H; out transposed [w][h]
    constexpr int R4 = TW,          C4 = R3;      // along W; final
    constexpr int PIN = IW, PA = r4_(R1), PB = r4_(R2), PA2 = r4_(R3);
    static_assert((long)C3 * PA2 <= (long)C1 * PA, "A2 aliases A");
    constexpr int NH1 = pickNH(R1, C1, NT), NH2 = pickNH(R2, C2, NT);
    constexpr int NH3 = pickNH(R3, C3, NT), NH4 = pickNH(R4, C4, NT);
    static_assert(cdiv_(R4, NH4) * C4 <= NT, "p4 must be single-item");

    __shared__ float smem[IH * PIN + C1 * PA + C2 * PB];
    float* bufIn = smem;
    float* A = smem + IH * PIN;
    float* B = A + C1 * PA;
    float* A2 = A; // p3 output reuses A's space (A dead after p2)

    const int tid = threadIdx.x;
    const int b = blockIdx.z >> 5, ch = blockIdx.z & 31;
    const int h0 = blockIdx.y * TH, w0 = blockIdx.x * TW;

    const float kmul = coef[ch];          // k  = fbase * coef
    const float kcmul = kmul * cin[ch];   // kc = k * c
    const float av = ain[ch];

    // ---- stage input tile (edge-clamped = "edge" padding) ----
    const float* xb = x + (b * HH * WW) * SCST + SI * CHN + ch;
    constexpr int NLOAD = cdiv_(IH * IW, NT);
#pragma unroll
    for (int t = 0; t < NLOAD; ++t) {
        int idx = tid + t * NT;
        if (idx < IH * IW) {
            int r = idx / IW, c = idx - r * IW;
            int gh = min(max(h0 + r - 2 * SW, 0), HH - 1);
            int gw = min(max(w0 + c - 2 * SW, 0), WW - 1);
            bufIn[r * PIN + c] = xb[(gh * WW + gw) * SCST];
        }
    }
    __syncthreads();

    const int c4 = tid % C4;
    const int r04 = (tid / C4) * NH4;
    const bool act4 = tid < cdiv_(R4, NH4) * C4;

    float xcv[NH4];
    // ---- closing: dilH, dilW, eroH, eroW ----
    pass_lds<L, SW, SI, true,  NH1, R1, C1, PIN, PA,  NT>(bufIn, A, kmul, tid);  __syncthreads();
    pass_lds<L, SW, SI, true,  NH2, R2, C2, PA,  PB,  NT>(A,     B, kmul, tid);  __syncthreads();
    pass_lds<L, SW, SI, false, NH3, R3, C3, PB,  PA2, NT>(B,    A2, kcmul, tid); __syncthreads();
    if (act4) pass_compute_si<L, SW, SI, false, NH4, R4, PA2>(A2, r04, c4, kcmul, xcv);
    __syncthreads(); // protect A2 before opening overwrites A

    // ---- opening: eroH, eroW, dilH, dilW ---- (bufIn still intact)
    pass_lds<L, SW, SI, false, NH1, R1, C1, PIN, PA,  NT>(bufIn, A, kmul, tid);  __syncthreads();
    pass_lds<L, SW, SI, false, NH2, R2, C2, PA,  PB,  NT>(A,     B, kmul, tid);  __syncthreads();
    pass_lds<L, SW, SI, true,  NH3, R3, C3, PB,  PA2, NT>(B,    A2, kcmul, tid); __syncthreads();
    if (act4) {
        float xov[NH4];
        pass_compute_si<L, SW, SI, true, NH4, R4, PA2>(A2, r04, c4, kcmul, xov);
        const int h = h0 + c4;
        float* ob = out + ((b * HH + h) * WW) * SCST + SI * CHN + ch;
#pragma unroll
        for (int o = 0; o < NH4; ++o) {
            int w = w0 + r04 + o;
            if (r04 + o < R4 && w < WW)
                ob[w * SCST] = av * xcv[o] + (1.0f - av) * xov[o];
        }
    }
}

extern "C" void kernel_launch(void* const* d_in, const int* in_sizes, int n_in,
                              void* d_out, int out_size, void* d_ws, size_t ws_size,
                              hipStream_t stream) {
    const float* x    = (const float*)d_in[0];
    const float* coef = (const float*)d_in[1];
    const float* cv   = (const float*)d_in[2];
    const float* av   = (const float*)d_in[3];
    float* out = (float*)d_out;
    (void)d_ws; (void)ws_size; (void)in_sizes; (void)n_in; (void)out_size;

    // scale 0: s=1  (L=3),  tile 64x64, LDS ~55KB  -> 2 blocks/CU (MW=8)
    lasry_kernel<0, 1, 64, 64, 1024, 8><<<dim3(3, 3, 256), 1024, 0, stream>>>(x, coef, cv, av, out);
    // scale 1: s=3  (L=7),  tile 64x64, LDS ~65KB  -> 2 blocks/CU (MW=8)
    lasry_kernel<1, 3, 64, 64, 1024, 8><<<dim3(3, 3, 256), 1024, 0, stream>>>(x, coef, cv, av, out);
    // scale 2: s=8  (L=17), tile 64x64, LDS ~93KB  -> 1 block/CU (MW=4)
    lasry_kernel<2, 8, 64, 64, 1024, 4><<<dim3(3, 3, 256), 1024, 0, stream>>>(x, coef, cv, av, out);
    // scale 3: s=18 (L=37), tile 64x48, LDS ~147KB -> 1 block/CU (MW=4)
    lasry_kernel<3, 18, 64, 48, 1024, 4><<<dim3(4, 3, 256), 1024, 0, stream>>>(x, coef, cv, av, out);
}

// Round 2
// 758.975 us; speedup vs baseline: 1.9392x; 1.9392x over previous
//
#include <hip/hip_runtime.h>

// ScaleLasryLions R2: per-scale 4-stage planar pipeline.
// closing = eroH(eroW(dilW(dilH x))), opening = dilH(dilW(eroW(eroH x)))
// (separable same-type passes commute, so this equals the reference order).
// K1: x (interleaved, lane=c) -> A=dilH, B=eroH   planar [c][b][h'][w], h' in H+2s
// K2: in-place on A: dilW then eroW (taps k, kc); on B: eroW then dilW
// K3: xc=eroH(A), xo=dilH(B), blend -> res planar
// K4: res planar -> out[..., SI, :] (128B chunks = full 64B lines)

constexpr int BB = 8, HH = 192, WW = 192, CHN = 32, SCST = 128;

constexpr float s2_of(int si) { // scale^2 for {0.25,0.75,1.75,3.75}
    return si == 0 ? 0.0625f : si == 1 ? 0.5625f : si == 2 ? 3.0625f : 14.0625f;
}
constexpr int cdiv_(int a, int b) { return (a + b - 1) / b; }

// ---------------- K1: H-pass from interleaved x ----------------
template <int SI, int SW, int NH, int MW>
__launch_bounds__(512, MW) __global__
void k_hpass1(const float* __restrict__ x, const float* __restrict__ coef,
              float* __restrict__ A, float* __restrict__ Bb) {
    constexpr int L = 2 * SW + 1, HA = HH + 2 * SW, WN = NH + 2 * SW;
    constexpr float S2 = s2_of(SI);
    const int tid = threadIdx.x;
    const int c = tid & 31, wl = tid >> 5;          // 32 c x 16 w
    const int w0 = blockIdx.x * 16;
    const int r0 = blockIdx.y * NH;
    const int b  = blockIdx.z;
    const float kmul = coef[c];

    float wb[WN];
    const float* xb = x + ((size_t)(b * HH) * WW + (w0 + wl)) * SCST + SI * CHN + c;
#pragma unroll
    for (int t = 0; t < WN; ++t) {
        int gh = r0 + t - 2 * SW;
        gh = gh < 0 ? 0 : (gh > HH - 1 ? HH - 1 : gh);
        wb[t] = xb[(size_t)gh * (WW * SCST)];
    }

    __shared__ float stg[NH][CHN][17];
    const int c2 = tid >> 4, w2 = tid & 15;

    { // dilation (taps +k)
        float acc[NH];
#pragma unroll
        for (int j = 0; j < L; ++j) {
            float v = (float)(j - SW);
            float tp = (-(v * v) / S2) * kmul;
#pragma unroll
            for (int o = 0; o < NH; ++o) {
                float t = wb[o + j] + tp;
                acc[o] = (j == 0) ? t : fmaxf(acc[o], t);
            }
        }
#pragma unroll
        for (int o = 0; o < NH; ++o) stg[o][c][wl] = acc[o];
    }
    __syncthreads();
#pragma unroll
    for (int o = 0; o < NH; ++o) {
        int r = r0 + o;
        if (r < HA) A[((size_t)(c2 * BB + b) * HA + r) * WW + w0 + w2] = stg[o][c2][w2];
    }
    __syncthreads();
    { // erosion (taps -k)
        float acc[NH];
#pragma unroll
        for (int j = 0; j < L; ++j) {
            float v = (float)(j - SW);
            float tp = (-(v * v) / S2) * kmul;
#pragma unroll
            for (int o = 0; o < NH; ++o) {
                float t = wb[o + j] - tp;
                acc[o] = (j == 0) ? t : fminf(acc[o], t);
            }
        }
#pragma unroll
        for (int o = 0; o < NH; ++o) stg[o][c][wl] = acc[o];
    }
    __syncthreads();
#pragma unroll
    for (int o = 0; o < NH; ++o) {
        int r = r0 + o;
        if (r < HA) Bb[((size_t)(c2 * BB + b) * HA + r) * WW + w0 + w2] = stg[o][c2][w2];
    }
}

// ---------------- K2: two W-passes, in-place ----------------
// BR=0 (closing branch, buffer A): dilW(+k) then eroW(-kc)
// BR=1 (opening branch, buffer B): eroW(-k) then dilW(+kc)
template <int SI, int SW, int BR>
__launch_bounds__(256, 4) __global__
void k_wpass2(float* __restrict__ P, const float* __restrict__ coef,
              const float* __restrict__ cin) {
    constexpr int L = 2 * SW + 1, HA = HH + 2 * SW, WE = WW + 2 * SW;
    constexpr int NQ1 = cdiv_(WE, 32), NQ2 = WW / 32;
    constexpr float S2 = s2_of(SI);
    __shared__ float inb[8][WW + 1];
    __shared__ float tmp[8][WE + 1];
    const int tid = threadIdx.x;
    const int rl = tid >> 5, l = tid & 31;
    const size_t row = (size_t)blockIdx.x * 8 + rl;
    float* Prow = P + row * WW;
    const int c = (int)(row / (size_t)(BB * HA));
    const float k1 = coef[c], k2 = coef[c] * cin[c];

    for (int i = l; i < WW; i += 32) inb[rl][i] = Prow[i];
    __syncthreads();
    { // pass 1: width W (clamp-padded) -> WE
        const int q0 = l * NQ1;
        float wbuf[NQ1 + 2 * SW];
#pragma unroll
        for (int t = 0; t < NQ1 + 2 * SW; ++t) {
            int idx = q0 + t - 2 * SW;
            idx = idx < 0 ? 0 : (idx > WW - 1 ? WW - 1 : idx);
            wbuf[t] = inb[rl][idx];
        }
        float acc[NQ1];
#pragma unroll
        for (int j = 0; j < L; ++j) {
            float v = (float)(j - SW);
            float tp = (-(v * v) / S2) * k1;
#pragma unroll
            for (int o = 0; o < NQ1; ++o) {
                float t = (BR == 0) ? wbuf[o + j] + tp : wbuf[o + j] - tp;
                acc[o] = (j == 0) ? t : ((BR == 0) ? fmaxf(acc[o], t) : fminf(acc[o], t));
            }
        }
#pragma unroll
        for (int o = 0; o < NQ1; ++o) {
            int q = q0 + o;
            if (q < WE) tmp[rl][q] = acc[o];
        }
    }
    __syncthreads();
    { // pass 2: WE -> W (VALID), opposite op, taps kc
        const int q0 = l * NQ2;
        float wbuf[NQ2 + 2 * SW];
#pragma unroll
        for (int t = 0; t < NQ2 + 2 * SW; ++t) wbuf[t] = tmp[rl][q0 + t];
        float acc[NQ2];
#pragma unroll
        for (int j = 0; j < L; ++j) {
            float v = (float)(j - SW);
            float tp = (-(v * v) / S2) * k2;
#pragma unroll
            for (int o = 0; o < NQ2; ++o) {
                float t = (BR == 0) ? wbuf[o + j] - tp : wbuf[o + j] + tp;
                acc[o] = (j == 0) ? t : ((BR == 0) ? fminf(acc[o], t) : fmaxf(acc[o], t));
            }
        }
#pragma unroll
        for (int o = 0; o < NQ2; ++o) Prow[q0 + o] = acc[o];
    }
}

// ---------------- K3: final H-pass + blend -> res planar ----------------
template <int SI, int SW, int MW>
__launch_bounds__(256, MW) __global__
void k_hpass3(const float* __restrict__ A, const float* __restrict__ Bb,
              const float* __restrict__ coef, const float* __restrict__ cin,
              const float* __restrict__ ain, float* __restrict__ res) {
    constexpr int L = 2 * SW + 1, HA = HH + 2 * SW, RS = 64, RT = RS + 2 * SW;
    constexpr float S2 = s2_of(SI);
    __shared__ float tile[RT][64 + 1];
    const int tid = threadIdx.x;
    const int p = blockIdx.z;            // plane = c*8+b
    const int c = p >> 3;
    const int w0 = blockIdx.x * 64, r0 = blockIdx.y * RS;
    const float kc = coef[c] * cin[c], av = ain[c];
    const int wl = tid & 63, rq = tid >> 6; // 4 groups x 16 rows

    const float* Ab = A + ((size_t)p * HA + r0) * WW + w0;
    for (int i = tid; i < RT * 64; i += 256) {
        int r = i >> 6, w = i & 63;
        tile[r][w] = Ab[(size_t)r * WW + w];
    }
    __syncthreads();
    float xc[16];
    {
        float wbuf[16 + 2 * SW];
#pragma unroll
        for (int t = 0; t < 16 + 2 * SW; ++t) wbuf[t] = tile[rq * 16 + t][wl];
#pragma unroll
        for (int j = 0; j < L; ++j) {
            float v = (float)(j - SW);
            float tp = (-(v * v) / S2) * kc;
#pragma unroll
            for (int o = 0; o < 16; ++o) {
                float t = wbuf[o + j] - tp; // erosion
                xc[o] = (j == 0) ? t : fminf(xc[o], t);
            }
        }
    }
    __syncthreads();
    const float* Bp = Bb + ((size_t)p * HA + r0) * WW + w0;
    for (int i = tid; i < RT * 64; i += 256) {
        int r = i >> 6, w = i & 63;
        tile[r][w] = Bp[(size_t)r * WW + w];
    }
    __syncthreads();
    float outv[16];
    {
        float wbuf[16 + 2 * SW];
#pragma unroll
        for (int t = 0; t < 16 + 2 * SW; ++t) wbuf[t] = tile[rq * 16 + t][wl];
        float xo[16];
#pragma unroll
        for (int j = 0; j < L; ++j) {
            float v = (float)(j - SW);
            float tp = (-(v * v) / S2) * kc;
#pragma unroll
            for (int o = 0; o < 16; ++o) {
                float t = wbuf[o + j] + tp; // dilation
                xo[o] = (j == 0) ? t : fmaxf(xo[o], t);
            }
        }
#pragma unroll
        for (int o = 0; o < 16; ++o) outv[o] = av * xc[o] + (1.0f - av) * xo[o];
    }
    float* rp = res + ((size_t)p * HH + r0) * WW + w0;
#pragma unroll
    for (int o = 0; o < 16; ++o) rp[(size_t)(rq * 16 + o) * WW + wl] = outv[o];
}

// ---------------- K4: planar res -> interleaved out ----------------
template <int SI>
__launch_bounds__(256, 8) __global__
void k_scatter(const float* __restrict__ res, float* __restrict__ out) {
    __shared__ float stg[CHN][33];
    const int tid = threadIdx.x;
    const int w0 = blockIdx.x * 32, h = blockIdx.y, b = blockIdx.z;
#pragma unroll
    for (int it = 0; it < 4; ++it) {
        int cc = (tid >> 5) + it * 8, w = tid & 31;
        stg[cc][w] = res[((size_t)(cc * BB + b) * HH + h) * WW + w0 + w];
    }
    __syncthreads();
#pragma unroll
    for (int it = 0; it < 4; ++it) {
        int w = (tid >> 5) + it * 8, cc = tid & 31;
        out[((size_t)(b * HH + h) * WW + w0 + w) * SCST + SI * CHN + cc] = stg[cc][w];
    }
}

// ---------------- Fallback: R1 fused kernel (used if ws too small) ----------------
constexpr int r4_(int a) { return (a + 3) & ~3; }
constexpr int pickNH(int R, int C, int NT) {
    for (int nh = 1; nh <= R; ++nh)
        if (cdiv_(R, nh) * C <= NT) return nh;
    return R;
}
template <int L, int SW, int SI, bool DIL, int NH, int R, int PIT>
__device__ __forceinline__ void pass_compute_si(const float* __restrict__ in, int r0, int c,
                                                float kmul, float (&acc)[NH]) {
    constexpr float S2 = s2_of(SI);
    float wb[NH + L - 1];
#pragma unroll
    for (int t = 0; t < NH + L - 1; ++t) {
        int rr = r0 + t;
        if (rr > R + L - 2) rr = R + L - 2;
        wb[t] = in[rr * PIT + c];
    }
#pragma unroll
    for (int j = 0; j < L; ++j) {
        float v = (float)(j - SW);
        float tp = (-(v * v) / S2) * kmul;
#pragma unroll
        for (int o = 0; o < NH; ++o) {
            float t = DIL ? wb[o + j] + tp : wb[o + j] - tp;
            if (j == 0) acc[o] = t;
            else acc[o] = DIL ? fmaxf(acc[o], t) : fminf(acc[o], t);
        }
    }
}
template <int L, int SW, int SI, bool DIL, int NH, int R, int C, int PIT, int POUT, int NT>
__device__ __forceinline__ void pass_lds(const float* __restrict__ in, float* __restrict__ outT,
                                         float kmul, int tid) {
    constexpr int nseg = cdiv_(R, NH);
    for (int item = tid; item < nseg * C; item += NT) {
        int c = item % C, r0 = (item / C) * NH;
        float acc[NH];
        pass_compute_si<L, SW, SI, DIL, NH, R, PIT>(in, r0, c, kmul, acc);
#pragma unroll
        for (int o = 0; o < NH; ++o)
            if (r0 + o < R) outT[c * POUT + (r0 + o)] = acc[o];
    }
}
template <int SI, int SW, int TH, int TW, int NT, int MW>
__launch_bounds__(NT, MW) __global__
void lasry_kernel(const float* __restrict__ x, const float* __restrict__ coef,
                  const float* __restrict__ cin, const float* __restrict__ ain,
                  float* __restrict__ out) {
    constexpr int L = 2 * SW + 1;
    constexpr int IH = TH + 4 * SW, IW = TW + 4 * SW;
    constexpr int R1 = TH + 2 * SW, C1 = IW;
    constexpr int R2 = TW + 2 * SW, C2 = R1;
    constexpr int R3 = TH,          C3 = R2;
    constexpr int R4 = TW,          C4 = R3;
    constexpr int PIN = IW, PA = r4_(R1), PB = r4_(R2), PA2 = r4_(R3);
    constexpr int NH1 = pickNH(R1, C1, NT), NH2 = pickNH(R2, C2, NT);
    constexpr int NH3 = pickNH(R3, C3, NT), NH4 = pickNH(R4, C4, NT);
    __shared__ float smem[IH * PIN + C1 * PA + C2 * PB];
    float* bufIn = smem;
    float* A = smem + IH * PIN;
    float* B = A + C1 * PA;
    float* A2 = A;
    const int tid = threadIdx.x;
    const int b = blockIdx.z >> 5, ch = blockIdx.z & 31;
    const int h0 = blockIdx.y * TH, w0 = blockIdx.x * TW;
    const float kmul = coef[ch];
    const float kcmul = kmul * cin[ch];
    const float av = ain[ch];
    const float* xb = x + (size_t)(b * HH * WW) * SCST + SI * CHN + ch;
    constexpr int NLOAD = cdiv_(IH * IW, NT);
#pragma unroll
    for (int t = 0; t < NLOAD; ++t) {
        int idx = tid + t * NT;
        if (idx < IH * IW) {
            int r = idx / IW, c = idx - r * IW;
            int gh = min(max(h0 + r - 2 * SW, 0), HH - 1);
            int gw = min(max(w0 + c - 2 * SW, 0), WW - 1);
            bufIn[r * PIN + c] = xb[(size_t)(gh * WW + gw) * SCST];
        }
    }
    __syncthreads();
    const int c4 = tid % C4;
    const int r04 = (tid / C4) * NH4;
    const bool act4 = tid < cdiv_(R4, NH4) * C4;
    float xcv[NH4];
    pass_lds<L, SW, SI, true,  NH1, R1, C1, PIN, PA,  NT>(bufIn, A, kmul, tid);  __syncthreads();
    pass_lds<L, SW, SI, true,  NH2, R2, C2, PA,  PB,  NT>(A,     B, kmul, tid);  __syncthreads();
    pass_lds<L, SW, SI, false, NH3, R3, C3, PB,  PA2, NT>(B,    A2, kcmul, tid); __syncthreads();
    if (act4) pass_compute_si<L, SW, SI, false, NH4, R4, PA2>(A2, r04, c4, kcmul, xcv);
    __syncthreads();
    pass_lds<L, SW, SI, false, NH1, R1, C1, PIN, PA,  NT>(bufIn, A, kmul, tid);  __syncthreads();
    pass_lds<L, SW, SI, false, NH2, R2, C2, PA,  PB,  NT>(A,     B, kmul, tid);  __syncthreads();
    pass_lds<L, SW, SI, true,  NH3, R3, C3, PB,  PA2, NT>(B,    A2, kcmul, tid); __syncthreads();
    if (act4) {
        float xov[NH4];
        pass_compute_si<L, SW, SI, true, NH4, R4, PA2>(A2, r04, c4, kcmul, xov);
        const int h = h0 + c4;
        float* ob = out + ((size_t)(b * HH + h) * WW) * SCST + SI * CHN + ch;
#pragma unroll
        for (int o = 0; o < NH4; ++o) {
            int w = w0 + r04 + o;
            if (r04 + o < R4 && w < WW) ob[(size_t)w * SCST] = av * xcv[o] + (1.0f - av) * xov[o];
        }
    }
}

// ---------------- host ----------------
template <int SI, int SW, int NH, int MW1>
static void launch_scale(const float* x, const float* coef, const float* cv, const float* av,
                         float* out, float* A, float* Bb, float* res, hipStream_t stream) {
    constexpr int HA = HH + 2 * SW;
    k_hpass1<SI, SW, NH, MW1><<<dim3(WW / 16, cdiv_(HA, NH), BB), 512, 0, stream>>>(x, coef, A, Bb);
    k_wpass2<SI, SW, 0><<<dim3(CHN * BB * HA / 8), 256, 0, stream>>>(A, coef, cv);
    k_wpass2<SI, SW, 1><<<dim3(CHN * BB * HA / 8), 256, 0, stream>>>(Bb, coef, cv);
    k_hpass3<SI, SW, 4><<<dim3(WW / 64, HH / 64, CHN * BB), 256, 0, stream>>>(A, Bb, coef, cv, av, res);
    k_scatter<SI><<<dim3(WW / 32, HH, BB), 256, 0, stream>>>(res, out);
}

extern "C" void kernel_launch(void* const* d_in, const int* in_sizes, int n_in,
                              void* d_out, int out_size, void* d_ws, size_t ws_size,
                              hipStream_t stream) {
    const float* x    = (const float*)d_in[0];
    const float* coef = (const float*)d_in[1];
    const float* cv   = (const float*)d_in[2];
    const float* av   = (const float*)d_in[3];
    float* out = (float*)d_out;
    (void)in_sizes; (void)n_in; (void)out_size;

    constexpr size_t BUFSZ = (size_t)CHN * BB * 228 * WW;           // floats (s=18 size)
    constexpr size_t RESSZ = (size_t)CHN * BB * HH * WW;            // floats
    constexpr size_t WS_NEED = (2 * BUFSZ + RESSZ) * sizeof(float); // ~127.4 MB

    if (ws_size >= WS_NEED) {
        float* A   = (float*)d_ws;
        float* Bb  = A + BUFSZ;
        float* res = A + 2 * BUFSZ;
        launch_scale<0, 1, 14, 4>(x, coef, cv, av, out, A, Bb, res, stream);
        launch_scale<1, 3, 18, 4>(x, coef, cv, av, out, A, Bb, res, stream);
        launch_scale<2, 8, 24, 4>(x, coef, cv, av, out, A, Bb, res, stream);
        launch_scale<3, 18, 24, 3>(x, coef, cv, av, out, A, Bb, res, stream);
    } else {
        // fallback: R1 fused kernels (no workspace needed)
        lasry_kernel<0, 1, 64, 64, 1024, 8><<<dim3(3, 3, 256), 1024, 0, stream>>>(x, coef, cv, av, out);
        lasry_kernel<1, 3, 64, 64, 1024, 8><<<dim3(3, 3, 256), 1024, 0, stream>>>(x, coef, cv, av, out);
        lasry_kernel<2, 8, 64, 64, 1024, 4><<<dim3(3, 3, 256), 1024, 0, stream>>>(x, coef, cv, av, out);
        lasry_kernel<3, 18, 64, 48, 1024, 4><<<dim3(4, 3, 256), 1024, 0, stream>>>(x, coef, cv, av, out);
    }
}